// Round 10
// baseline (739.934 us; speedup 1.0000x reference)
//
#include <hip/hip_runtime.h>
#include <hip/hip_bf16.h>

// Problem constants
#define BS 16
#define NN 512
#define DD 256
#define RR 2
#define M_TOT (BS * NN)   // 8192 rows
#define KCAT 768          // concat K = DD * (1 + RR)
#define NBLK 512

typedef __attribute__((ext_vector_type(8))) short short8;
typedef __attribute__((ext_vector_type(4))) float f32x4;
typedef const __attribute__((address_space(1))) unsigned int as1u32;
typedef __attribute__((address_space(3))) unsigned int as3u32;

// async global->LDS, 16B per lane; LDS dest = wave-uniform base + lane*16
#define GLDS16(g, l) \
  __builtin_amdgcn_global_load_lds((as1u32*)(g), (as3u32*)(l), 16, 0, 0)

static __device__ __forceinline__ ushort f2bf(float f) {
  __hip_bfloat16 h = __float2bfloat16(f);
  return *reinterpret_cast<ushort*>(&h);
}
static __device__ __forceinline__ uint pack2bf(float a, float b) {
  return (uint)f2bf(a) | ((uint)f2bf(b) << 16);
}

// ---------------------------------------------------------------------------
// Software grid barrier (regular launch; capacity >= grid guarantees
// placement: LDS 33KB -> 4 blocks/CU, VGPR<=128 via launch_bounds -> >=2
// blocks/CU -> >=512 resident). Bounded spin: on logic failure we produce
// wrong output (diagnosable), not a hung container.
// ---------------------------------------------------------------------------
static __device__ __forceinline__ void gbar(unsigned int* cnt, int idx) {
  __threadfence();   // release: block's writes visible device-wide
  __syncthreads();
  if (threadIdx.x == 0) {
    __hip_atomic_fetch_add(cnt + idx, 1u, __ATOMIC_ACQ_REL,
                           __HIP_MEMORY_SCOPE_AGENT);
    for (int spin = 0; spin < 2000000; ++spin) {
      if (__hip_atomic_load(cnt + idx, __ATOMIC_ACQUIRE,
                            __HIP_MEMORY_SCOPE_AGENT) >= NBLK)
        break;
      __builtin_amdgcn_s_sleep(16);
    }
  }
  __syncthreads();
  __threadfence();   // acquire: invalidate stale cache lines
}

// ---------------------------------------------------------------------------
// agg phase: agg[r,b][j][d] = (1/deg) * sum_i MT[j][i] * xT[d][i]
// u in [0,512): (dt 4) x (jt 4) x (rb 32). 128j x 64d tile, BK=32, dbuf LDS
// via global_load_lds. inv_deg computed in-block from bitsT popcount.
// ---------------------------------------------------------------------------
static __device__ __forceinline__ void agg_phase(
    int u, int t, const ushort* __restrict__ MT, const ushort* __restrict__ xTT,
    const unsigned long long* __restrict__ bitsT, ushort* __restrict__ Abig,
    char* smem) {
  ushort* As = reinterpret_cast<ushort*>(smem);          // [2][128*32] 16KB
  ushort* Bs = reinterpret_cast<ushort*>(smem + 16384);  // [2][64*32]   8KB
  float* ids = reinterpret_cast<float*>(smem + 24576);   // [128]

  int wv = t >> 6, ln = t & 63;
  int fr = ln & 15, fq = ln >> 4;
  int dt = u & 3, jt = (u >> 2) & 3, rb = u >> 4;
  int r = rb >> 4, b = rb & 15;
  int m_base = jt * 128, n_base = dt * 64;

  if (t < 128) {
    const unsigned long long* bp =
        bitsT + ((size_t)((r * BS + b) * NN) + m_base + t) * 8;
    int s = 0;
#pragma unroll
    for (int q = 0; q < 8; ++q) s += __popcll(bp[q]);
    ids[t] = 1.0f / (float)(s < 1 ? 1 : s);
  }

  const ushort* Ag = MT + ((size_t)((r * BS + b) * NN + m_base)) * NN;
  const ushort* Bg = xTT + ((size_t)(b * DD + n_base)) * NN;
  int srow = ln >> 2, scol = (ln & 3) * 8;

  f32x4 acc[4][2];
#pragma unroll
  for (int i = 0; i < 4; ++i)
#pragma unroll
    for (int jj = 0; jj < 2; ++jj) acc[i][jj] = (f32x4)(0.0f);

  // prologue: stage kt=0 into buf 0
#pragma unroll
  for (int q = 0; q < 2; ++q) {
    int c = wv * 2 + q;
    GLDS16(Ag + (size_t)(c * 16 + srow) * NN + scol, As + c * 512);
  }
  GLDS16(Bg + (size_t)(wv * 16 + srow) * NN + scol, Bs + wv * 512);
  __syncthreads();

  const int NT = NN / 32;  // 16
  int wm = wv >> 1, wn = wv & 1;
#pragma unroll 1
  for (int kt = 0; kt < NT; ++kt) {
    int cur = kt & 1;
    ushort* Ac = As + cur * 4096;
    ushort* Bc = Bs + cur * 2048;
    if (kt + 1 < NT) {
      int k0 = (kt + 1) * 32;
      ushort* An = As + (cur ^ 1) * 4096;
      ushort* Bn = Bs + (cur ^ 1) * 2048;
#pragma unroll
      for (int q = 0; q < 2; ++q) {
        int c = wv * 2 + q;
        GLDS16(Ag + (size_t)(c * 16 + srow) * NN + k0 + scol, An + c * 512);
      }
      GLDS16(Bg + (size_t)(wv * 16 + srow) * NN + k0 + scol, Bn + wv * 512);
    }
    short8 a[4], bb[2];
#pragma unroll
    for (int mi = 0; mi < 4; ++mi)
      a[mi] = *reinterpret_cast<const short8*>(
          &Ac[(wm * 64 + mi * 16 + fr) * 32 + fq * 8]);
#pragma unroll
    for (int ni = 0; ni < 2; ++ni)
      bb[ni] = *reinterpret_cast<const short8*>(
          &Bc[(wn * 32 + ni * 16 + fr) * 32 + fq * 8]);
#pragma unroll
    for (int mi = 0; mi < 4; ++mi)
#pragma unroll
      for (int ni = 0; ni < 2; ++ni)
        acc[mi][ni] = __builtin_amdgcn_mfma_f32_16x16x32_bf16(
            a[mi], bb[ni], acc[mi][ni], 0, 0, 0);
    __syncthreads();  // drains vmcnt: next buf staged; cur reads done
  }

#pragma unroll
  for (int mi = 0; mi < 4; ++mi) {
#pragma unroll
    for (int t4 = 0; t4 < 4; ++t4) {
      int jl = wm * 64 + mi * 16 + fq * 4 + t4;
      float idv = ids[jl];
      size_t rowoff =
          (size_t)(b * NN + m_base + jl) * KCAT + 256 + r * 256 + n_base;
#pragma unroll
      for (int ni = 0; ni < 2; ++ni) {
        int d = wn * 32 + ni * 16 + fr;
        Abig[rowoff + d] = f2bf(acc[mi][ni][t4] * idv);
      }
    }
  }
}

// ---------------------------------------------------------------------------
// main phase: out[m][e] = elu(bias[e] + sum_k Abig[m][k] * WT[e][k])
// u in [0,512): (e-tile 4) x (m-tile 128). 64x64 tile, BK=32, dbuf LDS.
// MODE 0: bf16 h -> hOut slice0 (stride 768) AND hT[b][e][j] (LDS transpose).
// MODE 1: fp32 out.
// ---------------------------------------------------------------------------
template <int MODE>
static __device__ __forceinline__ void main_phase(
    int u, int t, const ushort* __restrict__ A, const ushort* __restrict__ WT,
    const float* __restrict__ bias, ushort* __restrict__ hOut,
    ushort* __restrict__ hT, float* __restrict__ fOut, char* smem) {
  ushort* As = reinterpret_cast<ushort*>(smem);         // [2][64*32] 8KB
  ushort* Bs = reinterpret_cast<ushort*>(smem + 8192);  // [2][64*32] 8KB

  int wv = t >> 6, ln = t & 63;
  int fr = ln & 15, fq = ln >> 4;
  int m_base = (u >> 2) * 64, e_base = (u & 3) * 64;

  const ushort* Ag = A + (size_t)m_base * KCAT;
  const ushort* Bg = WT + (size_t)e_base * KCAT;
  int srow = ln >> 2, scol = (ln & 3) * 8;

  f32x4 acc[2][2];
#pragma unroll
  for (int i = 0; i < 2; ++i)
#pragma unroll
    for (int jj = 0; jj < 2; ++jj) acc[i][jj] = (f32x4)(0.0f);

  GLDS16(Ag + (size_t)(wv * 16 + srow) * KCAT + scol, As + wv * 512);
  GLDS16(Bg + (size_t)(wv * 16 + srow) * KCAT + scol, Bs + wv * 512);
  __syncthreads();

  const int NT = KCAT / 32;  // 24
  int wm = wv >> 1, wn = wv & 1;
#pragma unroll 1
  for (int kt = 0; kt < NT; ++kt) {
    int cur = kt & 1;
    ushort* Ac = As + cur * 2048;
    ushort* Bc = Bs + cur * 2048;
    if (kt + 1 < NT) {
      int k0 = (kt + 1) * 32;
      GLDS16(Ag + (size_t)(wv * 16 + srow) * KCAT + k0 + scol,
             As + (cur ^ 1) * 2048 + wv * 512);
      GLDS16(Bg + (size_t)(wv * 16 + srow) * KCAT + k0 + scol,
             Bs + (cur ^ 1) * 2048 + wv * 512);
    }
    short8 a[2], bb[2];
#pragma unroll
    for (int mi = 0; mi < 2; ++mi)
      a[mi] = *reinterpret_cast<const short8*>(
          &Ac[(wm * 32 + mi * 16 + fr) * 32 + fq * 8]);
#pragma unroll
    for (int ni = 0; ni < 2; ++ni)
      bb[ni] = *reinterpret_cast<const short8*>(
          &Bc[(wn * 32 + ni * 16 + fr) * 32 + fq * 8]);
#pragma unroll
    for (int mi = 0; mi < 2; ++mi)
#pragma unroll
      for (int ni = 0; ni < 2; ++ni)
        acc[mi][ni] = __builtin_amdgcn_mfma_f32_16x16x32_bf16(
            a[mi], bb[ni], acc[mi][ni], 0, 0, 0);
    __syncthreads();
  }

  float bsv[2];
#pragma unroll
  for (int ni = 0; ni < 2; ++ni)
    bsv[ni] = bias[e_base + wn * 32 + ni * 16 + fr];

  if (MODE == 1) {
#pragma unroll
    for (int mi = 0; mi < 2; ++mi)
#pragma unroll
      for (int t4 = 0; t4 < 4; ++t4) {
        int m = m_base + wm * 32 + mi * 16 + fq * 4 + t4;
#pragma unroll
        for (int ni = 0; ni < 2; ++ni) {
          int e = e_base + wn * 32 + ni * 16 + fr;
          float v = acc[mi][ni][t4] + bsv[ni];
          v = v > 0.0f ? v : expm1f(v);
          fOut[(size_t)m * DD + e] = v;
        }
      }
  } else {
    int b = m_base >> 9, j0 = m_base & (NN - 1);
    ushort* LT = reinterpret_cast<ushort*>(smem);  // [64][68], 8.7KB of 16KB
    ushort hv[2][2][4];
#pragma unroll
    for (int mi = 0; mi < 2; ++mi)
#pragma unroll
      for (int ni = 0; ni < 2; ++ni)
#pragma unroll
        for (int t4 = 0; t4 < 4; ++t4) {
          int m = m_base + wm * 32 + mi * 16 + fq * 4 + t4;
          int e = e_base + wn * 32 + ni * 16 + fr;
          float v = acc[mi][ni][t4] + bsv[ni];
          v = v > 0.0f ? v : expm1f(v);
          ushort uu = f2bf(v);
          hOut[(size_t)m * KCAT + e] = uu;
          hv[mi][ni][t4] = uu;
        }
    // transpose through LDS (final loop barrier already passed)
#pragma unroll
    for (int mi = 0; mi < 2; ++mi)
#pragma unroll
      for (int ni = 0; ni < 2; ++ni)
#pragma unroll
        for (int t4 = 0; t4 < 4; ++t4) {
          int ml = wm * 32 + mi * 16 + fq * 4 + t4;
          int el = wn * 32 + ni * 16 + fr;
          LT[el * 68 + ml] = hv[mi][ni][t4];
        }
    __syncthreads();
    int er = t >> 2, mq = (t & 3) * 16;
    ushort* dst = hT + ((size_t)(b * DD + e_base + er)) * NN + j0 + mq;
    int4 v0 = *reinterpret_cast<const int4*>(&LT[er * 68 + mq]);
    int4 v1 = *reinterpret_cast<const int4*>(&LT[er * 68 + mq + 8]);
    *reinterpret_cast<int4*>(dst) = v0;
    *reinterpret_cast<int4*>(dst + 8) = v1;
  }
}

// ---------------------------------------------------------------------------
// Megakernel (regular launch + software grid barrier):
// P0 [masks+MT | xprep] + wcat -> bar -> agg1 -> bar -> main1(+hT) -> bar ->
// agg2 -> bar -> main2. 512 blocks x 256 threads.
// ---------------------------------------------------------------------------
__global__ __launch_bounds__(256, 2) void mega_kernel(
    const float* __restrict__ x, const float* __restrict__ wrel1,
    const float* __restrict__ wroot1, const float* __restrict__ bias1,
    const float* __restrict__ wrel2, const float* __restrict__ wroot2,
    const float* __restrict__ bias2, const int* __restrict__ aug,
    const int* __restrict__ punct, float* __restrict__ out,
    unsigned int* __restrict__ sync, unsigned long long* __restrict__ bitsT,
    ushort* __restrict__ MT, ushort* __restrict__ xT,
    ushort* __restrict__ hT, ushort* __restrict__ W1,
    ushort* __restrict__ W2, ushort* __restrict__ Abig1,
    ushort* __restrict__ Abig2) {
  __shared__ __align__(16) char smem[33792];
  const int blk = blockIdx.x;
  const int t = threadIdx.x;

  // ================= P0 =================
  if (blk < 256) {
    // ---- masks + bits + MT expansion ----
    int jb = blk & 1, w = (blk >> 1) & 7, b = blk >> 4;
    int j = jb * 256 + t;
    long base = ((long)(b * NN + w * 64)) * NN + j;
    unsigned long long m0 = 0ull, m1 = 0ull;
#pragma unroll 16
    for (int k = 0; k < 64; ++k) {
      int a = aug[base + (long)k * NN];
      int p = punct[base + (long)k * NN];
      m1 |= (unsigned long long)(a == 1) << k;
      m0 |= (unsigned long long)((p == 1) & (a != 1)) << k;
    }
    bitsT[((size_t)((0 * BS + b) * NN + j)) * 8 + w] = m0;
    bitsT[((size_t)((1 * BS + b) * NN + j)) * 8 + w] = m1;
    ushort* r0 = MT + ((size_t)((0 * BS + b) * NN + j)) * NN + w * 64;
    ushort* r1 = MT + ((size_t)((1 * BS + b) * NN + j)) * NN + w * 64;
#pragma unroll
    for (int c = 0; c < 8; ++c) {
      uint w0[4], w1[4];
#pragma unroll
      for (int q = 0; q < 4; ++q) {
        int k0 = c * 8 + q * 2;
        w0[q] = (((m0 >> k0) & 1) ? 0x3F80u : 0u) |
                (((m0 >> (k0 + 1)) & 1) ? 0x3F800000u : 0u);
        w1[q] = (((m1 >> k0) & 1) ? 0x3F80u : 0u) |
                (((m1 >> (k0 + 1)) & 1) ? 0x3F800000u : 0u);
      }
      *reinterpret_cast<int4*>(r0 + c * 8) = *reinterpret_cast<int4*>(w0);
      *reinterpret_cast<int4*>(r1 + c * 8) = *reinterpret_cast<int4*>(w1);
    }
  } else {
    // ---- xprep: x -> Abig1 slice0 + xT ----
    int u = blk - 256;
    int b = u >> 4, i0 = (u & 15) * 32;
    float(*tile)[260] = reinterpret_cast<float(*)[260]>(smem);
    int il = t >> 3, c0 = (t & 7) * 32;
    const float* src = x + ((size_t)(b * NN + i0 + il)) * DD + c0;
#pragma unroll
    for (int q = 0; q < 8; ++q) {
      float4 v = *reinterpret_cast<const float4*>(src + q * 4);
      *reinterpret_cast<float4*>(&tile[il][c0 + q * 4]) = v;
    }
    __syncthreads();
    ushort* dst = Abig1 + (size_t)(b * NN + i0 + il) * KCAT + c0;
#pragma unroll
    for (int q = 0; q < 4; ++q) {
      uint pk[4];
#pragma unroll
      for (int p2 = 0; p2 < 4; ++p2)
        pk[p2] = pack2bf(tile[il][c0 + q * 8 + p2 * 2],
                         tile[il][c0 + q * 8 + p2 * 2 + 1]);
      *reinterpret_cast<int4*>(dst + q * 8) = *reinterpret_cast<int4*>(pk);
    }
    int d = t;
    ushort tmp[32];
#pragma unroll
    for (int ii = 0; ii < 32; ++ii) tmp[ii] = f2bf(tile[ii][d]);
    ushort* dT = xT + ((size_t)(b * DD + d)) * NN + i0;
#pragma unroll
    for (int q = 0; q < 4; ++q)
      *reinterpret_cast<int4*>(dT + q * 8) =
          *reinterpret_cast<int4*>(&tmp[q * 8]);
  }
  __syncthreads();  // LDS handoff before wcat
  if (blk < 384) {
    // ---- wcat: WcatT[e][s*256+d] = W_s[d][e], both layers ----
    int layer = blk / 192, rem = blk % 192, s = rem / 64, t2 = rem % 64;
    int d0 = (t2 >> 3) * 32, e0 = (t2 & 7) * 32;
    const float* root = layer ? wroot2 : wroot1;
    const float* rel = layer ? wrel2 : wrel1;
    ushort* dst = layer ? W2 : W1;
    const float* src = (s == 0) ? root : (rel + (size_t)(s - 1) * DD * DD);
    float(*tl)[33] = reinterpret_cast<float(*)[33]>(smem);
    int tx = t & 31, ty = t >> 5;
#pragma unroll
    for (int q = 0; q < 4; ++q) {
      int dl = ty + q * 8;
      tl[dl][tx] = src[(size_t)(d0 + dl) * DD + e0 + tx];
    }
    __syncthreads();
#pragma unroll
    for (int q = 0; q < 4; ++q) {
      int el = ty + q * 8;
      dst[(size_t)(e0 + el) * KCAT + s * 256 + d0 + tx] = f2bf(tl[tx][el]);
    }
  }
  gbar(sync, 0);
  // ================= P1: agg layer 1 =================
  agg_phase(blk, t, MT, xT, bitsT, Abig1, smem);
  gbar(sync, 1);
  // ================= P2: main layer 1 =================
  main_phase<0>(blk, t, Abig1, W1, bias1, Abig2, hT, nullptr, smem);
  gbar(sync, 2);
  // ================= P3: agg layer 2 =================
  agg_phase(blk, t, MT, hT, bitsT, Abig2, smem);
  gbar(sync, 3);
  // ================= P4: main layer 2 =================
  main_phase<1>(blk, t, Abig2, W2, bias2, nullptr, nullptr, out, smem);
}

extern "C" void kernel_launch(void* const* d_in, const int* in_sizes, int n_in,
                              void* d_out, int out_size, void* d_ws,
                              size_t ws_size, hipStream_t stream) {
  const float* x = (const float*)d_in[0];
  const float* w_rel1 = (const float*)d_in[1];
  const float* w_root1 = (const float*)d_in[2];
  const float* b1 = (const float*)d_in[3];
  const float* w_rel2 = (const float*)d_in[4];
  const float* w_root2 = (const float*)d_in[5];
  const float* b2 = (const float*)d_in[6];
  const int* aug = (const int*)d_in[7];
  const int* punct = (const int*)d_in[8];
  float* out = (float*)d_out;

  char* ws = (char*)d_ws;
  size_t off = 0;
  unsigned int* sync = (unsigned int*)(ws + off);  off += 256;  // 4 counters
  unsigned long long* bitsT = (unsigned long long*)(ws + off);
  off += (size_t)RR * BS * NN * 8 * 8;                          // 1 MB
  ushort* MT = (ushort*)(ws + off);  off += (size_t)RR * BS * NN * NN * 2;  // 16 MB
  ushort* xT = (ushort*)(ws + off);  off += (size_t)BS * DD * NN * 2;       // 4 MB
  ushort* hT = (ushort*)(ws + off);  off += (size_t)BS * DD * NN * 2;       // 4 MB
  ushort* W1 = (ushort*)(ws + off);  off += (size_t)DD * KCAT * 2;          // 384 KB
  ushort* W2 = (ushort*)(ws + off);  off += (size_t)DD * KCAT * 2;          // 384 KB
  ushort* Abig1 = (ushort*)(ws + off); off += (size_t)M_TOT * KCAT * 2;     // 12 MB
  ushort* Abig2 = (ushort*)(ws + off); off += (size_t)M_TOT * KCAT * 2;     // 12 MB

  // zero the barrier counters (graph-capture-safe memset node)
  hipMemsetAsync(sync, 0, 256, stream);

  mega_kernel<<<dim3(NBLK), dim3(256), 0, stream>>>(
      x, w_rel1, w_root1, b1, w_rel2, w_root2, b2, aug, punct, out, sync,
      bitsT, MT, xT, hT, W1, W2, Abig1, Abig2);
}

// Round 11
// 167.999 us; speedup vs baseline: 4.4044x; 4.4044x over previous
//
#include <hip/hip_runtime.h>
#include <hip/hip_bf16.h>

// Problem constants
#define BS 16
#define NN 512
#define DD 256
#define RR 2
#define M_TOT (BS * NN)   // 8192 rows
#define KCAT 768          // concat K = DD * (1 + RR)

typedef __attribute__((ext_vector_type(8))) short short8;
typedef __attribute__((ext_vector_type(4))) float f32x4;
typedef const __attribute__((address_space(1))) unsigned int as1u32;
typedef __attribute__((address_space(3))) unsigned int as3u32;

// async global->LDS, 16B per lane; LDS dest = wave-uniform base + lane*16
#define GLDS16(g, l) \
  __builtin_amdgcn_global_load_lds((as1u32*)(g), (as3u32*)(l), 16, 0, 0)

static __device__ __forceinline__ ushort f2bf(float f) {
  __hip_bfloat16 h = __float2bfloat16(f);
  return *reinterpret_cast<ushort*>(&h);
}
static __device__ __forceinline__ uint pack2bf(float a, float b) {
  return (uint)f2bf(a) | ((uint)f2bf(b) << 16);
}

// ---------------------------------------------------------------------------
// LDS swizzle (both-sides, rule #21): tiles are [rows][32] ushort, row = 64 B
// = 4 x 16B slots. Linear layout makes ds_read_b128 (16 lanes, 64B stride) an
// 8-way bank conflict (3.6M counted in r10). Rotate the 16B-slot index by
// ((row&15)>>1)&3: stage side pre-rotates the per-lane GLOBAL source column
// (gload_lds LDS dest is fixed linear); read side applies the same rotation.
// 16 consecutive rows then hit 8 distinct bank-groups (2-way = free).
//   stage: lane ln fetches logical col16 = ((ln&3) - (ln>>3)) & 3
//   read : logical col16 fq lives at phys ((fq + ((fr>>1)&3)) & 3)
// ---------------------------------------------------------------------------

// ---------------------------------------------------------------------------
// prep kernel, 512 blocks x 256 threads:
//   blk <  256: masks -> bitsT + inline MT bf16 expansion
//   blk >= 256: xprep (x -> Abig1 slice0 + xT)
//   then blk < 384: wcat (WcatT[e][s*256+d] = W_s[d][e], both layers)
// ---------------------------------------------------------------------------
__global__ __launch_bounds__(256) void prep_kernel(
    const float* __restrict__ x, const float* __restrict__ wrel1,
    const float* __restrict__ wroot1, const float* __restrict__ wrel2,
    const float* __restrict__ wroot2, const int* __restrict__ aug,
    const int* __restrict__ punct, unsigned long long* __restrict__ bitsT,
    ushort* __restrict__ MT, ushort* __restrict__ xT,
    ushort* __restrict__ Abig1, ushort* __restrict__ W1,
    ushort* __restrict__ W2) {
  __shared__ __align__(16) char smem[33792];
  const int blk = blockIdx.x;
  const int t = threadIdx.x;

  if (blk < 256) {
    // ---- masks + bits + MT expansion ----
    int jb = blk & 1, w = (blk >> 1) & 7, b = blk >> 4;
    int j = jb * 256 + t;
    long base = ((long)(b * NN + w * 64)) * NN + j;
    unsigned long long m0 = 0ull, m1 = 0ull;
#pragma unroll 16
    for (int k = 0; k < 64; ++k) {
      int a = aug[base + (long)k * NN];
      int p = punct[base + (long)k * NN];
      m1 |= (unsigned long long)(a == 1) << k;
      m0 |= (unsigned long long)((p == 1) & (a != 1)) << k;
    }
    bitsT[((size_t)((0 * BS + b) * NN + j)) * 8 + w] = m0;
    bitsT[((size_t)((1 * BS + b) * NN + j)) * 8 + w] = m1;
    ushort* r0 = MT + ((size_t)((0 * BS + b) * NN + j)) * NN + w * 64;
    ushort* r1 = MT + ((size_t)((1 * BS + b) * NN + j)) * NN + w * 64;
#pragma unroll
    for (int c = 0; c < 8; ++c) {
      uint w0[4], w1[4];
#pragma unroll
      for (int q = 0; q < 4; ++q) {
        int k0 = c * 8 + q * 2;
        w0[q] = (((m0 >> k0) & 1) ? 0x3F80u : 0u) |
                (((m0 >> (k0 + 1)) & 1) ? 0x3F800000u : 0u);
        w1[q] = (((m1 >> k0) & 1) ? 0x3F80u : 0u) |
                (((m1 >> (k0 + 1)) & 1) ? 0x3F800000u : 0u);
      }
      *reinterpret_cast<int4*>(r0 + c * 8) = *reinterpret_cast<int4*>(w0);
      *reinterpret_cast<int4*>(r1 + c * 8) = *reinterpret_cast<int4*>(w1);
    }
  } else {
    // ---- xprep: x -> Abig1 slice0 + xT ----
    int u = blk - 256;
    int b = u >> 4, i0 = (u & 15) * 32;
    float(*tile)[260] = reinterpret_cast<float(*)[260]>(smem);
    int il = t >> 3, c0 = (t & 7) * 32;
    const float* src = x + ((size_t)(b * NN + i0 + il)) * DD + c0;
#pragma unroll
    for (int q = 0; q < 8; ++q) {
      float4 v = *reinterpret_cast<const float4*>(src + q * 4);
      *reinterpret_cast<float4*>(&tile[il][c0 + q * 4]) = v;
    }
    __syncthreads();
    ushort* dst = Abig1 + (size_t)(b * NN + i0 + il) * KCAT + c0;
#pragma unroll
    for (int q = 0; q < 4; ++q) {
      uint pk[4];
#pragma unroll
      for (int p2 = 0; p2 < 4; ++p2)
        pk[p2] = pack2bf(tile[il][c0 + q * 8 + p2 * 2],
                         tile[il][c0 + q * 8 + p2 * 2 + 1]);
      *reinterpret_cast<int4*>(dst + q * 8) = *reinterpret_cast<int4*>(pk);
    }
    int d = t;
    ushort tmp[32];
#pragma unroll
    for (int ii = 0; ii < 32; ++ii) tmp[ii] = f2bf(tile[ii][d]);
    ushort* dT = xT + ((size_t)(b * DD + d)) * NN + i0;
#pragma unroll
    for (int q = 0; q < 4; ++q)
      *reinterpret_cast<int4*>(dT + q * 8) =
          *reinterpret_cast<int4*>(&tmp[q * 8]);
  }
  __syncthreads();  // LDS handoff before wcat
  if (blk < 384) {
    // ---- wcat: WcatT[e][s*256+d] = W_s[d][e], both layers ----
    int layer = blk / 192, rem = blk % 192, s = rem / 64, t2 = rem % 64;
    int d0 = (t2 >> 3) * 32, e0 = (t2 & 7) * 32;
    const float* root = layer ? wroot2 : wroot1;
    const float* rel = layer ? wrel2 : wrel1;
    ushort* dst = layer ? W2 : W1;
    const float* src = (s == 0) ? root : (rel + (size_t)(s - 1) * DD * DD);
    float(*tl)[33] = reinterpret_cast<float(*)[33]>(smem);
    int tx = t & 31, ty = t >> 5;
#pragma unroll
    for (int q = 0; q < 4; ++q) {
      int dl = ty + q * 8;
      tl[dl][tx] = src[(size_t)(d0 + dl) * DD + e0 + tx];
    }
    __syncthreads();
#pragma unroll
    for (int q = 0; q < 4; ++q) {
      int el = ty + q * 8;
      dst[(size_t)(e0 + el) * KCAT + s * 256 + d0 + tx] = f2bf(tl[tx][el]);
    }
  }
}

// ---------------------------------------------------------------------------
// agg GEMM: agg[r,b][j][d] = (1/deg) * sum_i MT[j][i] * xT[d][i]
// 128j x 64d tile, BK=32, dbuf LDS via gload_lds (swizzled), 1 barrier/kt.
// grid (4 d, 4 j, 32 rb) = 512 blocks. inv_deg from bitsT popcount in-block.
// Output -> Abig[(b*512+j)*768 + 256 + r*256 + d] (bf16).
// ---------------------------------------------------------------------------
__global__ __launch_bounds__(256) void agg_gemm_kernel(
    const unsigned long long* __restrict__ bitsT,
    const ushort* __restrict__ MT, const ushort* __restrict__ xT,
    ushort* __restrict__ Abig) {
  __shared__ __align__(16) ushort As[2][128 * 32];  // 16 KB
  __shared__ __align__(16) ushort Bs[2][64 * 32];   // 8 KB
  __shared__ float ids[128];
  int t = threadIdx.x;
  int wv = t >> 6, ln = t & 63;
  int fr = ln & 15, fq = ln >> 4;
  int rb = blockIdx.z, r = rb >> 4, b = rb & 15;
  int m_base = blockIdx.y * 128, n_base = blockIdx.x * 64;

  if (t < 128) {
    const unsigned long long* bp =
        bitsT + ((size_t)((r * BS + b) * NN) + m_base + t) * 8;
    int s = 0;
#pragma unroll
    for (int q = 0; q < 8; ++q) s += __popcll(bp[q]);
    ids[t] = 1.0f / (float)(s < 1 ? 1 : s);
  }

  const ushort* Ag = MT + ((size_t)((r * BS + b) * NN + m_base)) * NN;
  const ushort* Bg = xT + ((size_t)(b * DD + n_base)) * NN;
  int srow = ln >> 2;
  int scol = (((ln & 3) - (ln >> 3)) & 3) * 8;  // swizzled source col16

  f32x4 acc[4][2];
#pragma unroll
  for (int i = 0; i < 4; ++i)
#pragma unroll
    for (int jj = 0; jj < 2; ++jj) acc[i][jj] = (f32x4)(0.0f);

  // prologue: stage kt=0 into buf 0
#pragma unroll
  for (int q = 0; q < 2; ++q) {
    int c = wv * 2 + q;
    GLDS16(Ag + (size_t)(c * 16 + srow) * NN + scol, As[0] + c * 512);
  }
  GLDS16(Bg + (size_t)(wv * 16 + srow) * NN + scol, Bs[0] + wv * 512);
  __syncthreads();

  const int NT = NN / 32;  // 16
  int wm = wv >> 1, wn = wv & 1;
  int rot = (fr >> 1) & 3;
  int cA = ((fq + rot) & 3) * 8;  // swizzled read col (ushorts)
#pragma unroll 1
  for (int kt = 0; kt < NT; ++kt) {
    int cur = kt & 1;
    const ushort* Ac = As[cur];
    const ushort* Bc = Bs[cur];
    if (kt + 1 < NT) {
      int k0 = (kt + 1) * 32;
      ushort* An = As[cur ^ 1];
      ushort* Bn = Bs[cur ^ 1];
#pragma unroll
      for (int q = 0; q < 2; ++q) {
        int c = wv * 2 + q;
        GLDS16(Ag + (size_t)(c * 16 + srow) * NN + k0 + scol, An + c * 512);
      }
      GLDS16(Bg + (size_t)(wv * 16 + srow) * NN + k0 + scol, Bn + wv * 512);
    }
    short8 a[4], bb[2];
#pragma unroll
    for (int mi = 0; mi < 4; ++mi)
      a[mi] = *reinterpret_cast<const short8*>(
          &Ac[(wm * 64 + mi * 16 + fr) * 32 + cA]);
#pragma unroll
    for (int ni = 0; ni < 2; ++ni)
      bb[ni] = *reinterpret_cast<const short8*>(
          &Bc[(wn * 32 + ni * 16 + fr) * 32 + cA]);
#pragma unroll
    for (int mi = 0; mi < 4; ++mi)
#pragma unroll
      for (int ni = 0; ni < 2; ++ni)
        acc[mi][ni] = __builtin_amdgcn_mfma_f32_16x16x32_bf16(
            a[mi], bb[ni], acc[mi][ni], 0, 0, 0);
    __syncthreads();  // drains vmcnt: next buf staged; cur reads done
  }

#pragma unroll
  for (int mi = 0; mi < 4; ++mi) {
#pragma unroll
    for (int t4 = 0; t4 < 4; ++t4) {
      int jl = wm * 64 + mi * 16 + fq * 4 + t4;
      float idv = ids[jl];
      size_t rowoff =
          (size_t)(b * NN + m_base + jl) * KCAT + 256 + r * 256 + n_base;
#pragma unroll
      for (int ni = 0; ni < 2; ++ni) {
        int d = wn * 32 + ni * 16 + fr;
        Abig[rowoff + d] = f2bf(acc[mi][ni][t4] * idv);
      }
    }
  }
}

// ---------------------------------------------------------------------------
// main GEMM: out[m][e] = elu(bias[e] + sum_k Abig[m][k] * WT[e][k])
// 64x64 tile, BK=32, dbuf LDS via gload_lds (swizzled). grid (4 e, 128 m).
// MODE 0: bf16 h -> hOut slice0 (stride 768) AND hT[b][e][j] (LDS transpose).
// MODE 1: fp32 out.
// ---------------------------------------------------------------------------
template <int MODE>
__global__ __launch_bounds__(256) void main_gemm_kernel(
    const ushort* __restrict__ A, const ushort* __restrict__ WT,
    const float* __restrict__ bias, ushort* __restrict__ hOut,
    ushort* __restrict__ hT, float* __restrict__ fOut) {
  __shared__ __align__(16) ushort As[2][64 * 32];  // 8 KB (also LT reuse)
  __shared__ __align__(16) ushort Bs[2][64 * 32];  // 8 KB
  int t = threadIdx.x;
  int wv = t >> 6, ln = t & 63;
  int fr = ln & 15, fq = ln >> 4;
  int m_base = blockIdx.y * 64, e_base = blockIdx.x * 64;

  const ushort* Ag = A + (size_t)m_base * KCAT;
  const ushort* Bg = WT + (size_t)e_base * KCAT;
  int srow = ln >> 2;
  int scol = (((ln & 3) - (ln >> 3)) & 3) * 8;  // swizzled source col16

  f32x4 acc[2][2];
#pragma unroll
  for (int i = 0; i < 2; ++i)
#pragma unroll
    for (int jj = 0; jj < 2; ++jj) acc[i][jj] = (f32x4)(0.0f);

  GLDS16(Ag + (size_t)(wv * 16 + srow) * KCAT + scol, As[0] + wv * 512);
  GLDS16(Bg + (size_t)(wv * 16 + srow) * KCAT + scol, Bs[0] + wv * 512);
  __syncthreads();

  const int NT = KCAT / 32;  // 24
  int wm = wv >> 1, wn = wv & 1;
  int rot = (fr >> 1) & 3;
  int cA = ((fq + rot) & 3) * 8;
#pragma unroll 1
  for (int kt = 0; kt < NT; ++kt) {
    int cur = kt & 1;
    const ushort* Ac = As[cur];
    const ushort* Bc = Bs[cur];
    if (kt + 1 < NT) {
      int k0 = (kt + 1) * 32;
      GLDS16(Ag + (size_t)(wv * 16 + srow) * KCAT + k0 + scol,
             As[cur ^ 1] + wv * 512);
      GLDS16(Bg + (size_t)(wv * 16 + srow) * KCAT + k0 + scol,
             Bs[cur ^ 1] + wv * 512);
    }
    short8 a[2], bb[2];
#pragma unroll
    for (int mi = 0; mi < 2; ++mi)
      a[mi] = *reinterpret_cast<const short8*>(
          &Ac[(wm * 32 + mi * 16 + fr) * 32 + cA]);
#pragma unroll
    for (int ni = 0; ni < 2; ++ni)
      bb[ni] = *reinterpret_cast<const short8*>(
          &Bc[(wn * 32 + ni * 16 + fr) * 32 + cA]);
#pragma unroll
    for (int mi = 0; mi < 2; ++mi)
#pragma unroll
      for (int ni = 0; ni < 2; ++ni)
        acc[mi][ni] = __builtin_amdgcn_mfma_f32_16x16x32_bf16(
            a[mi], bb[ni], acc[mi][ni], 0, 0, 0);
    __syncthreads();
  }

  float bsv[2];
#pragma unroll
  for (int ni = 0; ni < 2; ++ni)
    bsv[ni] = bias[e_base + wn * 32 + ni * 16 + fr];

  if (MODE == 1) {
#pragma unroll
    for (int mi = 0; mi < 2; ++mi)
#pragma unroll
      for (int t4 = 0; t4 < 4; ++t4) {
        int m = m_base + wm * 32 + mi * 16 + fq * 4 + t4;
#pragma unroll
        for (int ni = 0; ni < 2; ++ni) {
          int e = e_base + wn * 32 + ni * 16 + fr;
          float v = acc[mi][ni][t4] + bsv[ni];
          v = v > 0.0f ? v : expm1f(v);
          fOut[(size_t)m * DD + e] = v;
        }
      }
  } else {
    int b = m_base >> 9, j0 = m_base & (NN - 1);
    ushort* LT = &As[0][0];  // reuse as [64][68]
    ushort hv[2][2][4];
#pragma unroll
    for (int mi = 0; mi < 2; ++mi)
#pragma unroll
      for (int ni = 0; ni < 2; ++ni)
#pragma unroll
        for (int t4 = 0; t4 < 4; ++t4) {
          int m = m_base + wm * 32 + mi * 16 + fq * 4 + t4;
          int e = e_base + wn * 32 + ni * 16 + fr;
          float v = acc[mi][ni][t4] + bsv[ni];
          v = v > 0.0f ? v : expm1f(v);
          ushort u = f2bf(v);
          hOut[(size_t)m * KCAT + e] = u;
          hv[mi][ni][t4] = u;
        }
#pragma unroll
    for (int mi = 0; mi < 2; ++mi)
#pragma unroll
      for (int ni = 0; ni < 2; ++ni)
#pragma unroll
        for (int t4 = 0; t4 < 4; ++t4) {
          int ml = wm * 32 + mi * 16 + fq * 4 + t4;
          int el = wn * 32 + ni * 16 + fr;
          LT[el * 68 + ml] = hv[mi][ni][t4];
        }
    __syncthreads();
    int er = t >> 2, mq = (t & 3) * 16;
    ushort* dst = hT + ((size_t)(b * DD + e_base + er)) * NN + j0 + mq;
    int4 v0 = *reinterpret_cast<const int4*>(&LT[er * 68 + mq]);
    int4 v1 = *reinterpret_cast<const int4*>(&LT[er * 68 + mq + 8]);
    *reinterpret_cast<int4*>(dst) = v0;
    *reinterpret_cast<int4*>(dst + 8) = v1;
  }
}

extern "C" void kernel_launch(void* const* d_in, const int* in_sizes, int n_in,
                              void* d_out, int out_size, void* d_ws,
                              size_t ws_size, hipStream_t stream) {
  const float* x = (const float*)d_in[0];
  const float* w_rel1 = (const float*)d_in[1];
  const float* w_root1 = (const float*)d_in[2];
  const float* b1 = (const float*)d_in[3];
  const float* w_rel2 = (const float*)d_in[4];
  const float* w_root2 = (const float*)d_in[5];
  const float* b2 = (const float*)d_in[6];
  const int* aug = (const int*)d_in[7];
  const int* punct = (const int*)d_in[8];
  float* out = (float*)d_out;

  char* ws = (char*)d_ws;
  size_t off = 0;
  unsigned long long* bitsT = (unsigned long long*)(ws + off);
  off += (size_t)RR * BS * NN * 8 * 8;                                      // 1 MB
  ushort* MT = (ushort*)(ws + off);  off += (size_t)RR * BS * NN * NN * 2;  // 16 MB
  ushort* xT = (ushort*)(ws + off);  off += (size_t)BS * DD * NN * 2;       // 4 MB
  ushort* hT = (ushort*)(ws + off);  off += (size_t)BS * DD * NN * 2;       // 4 MB
  ushort* W1 = (ushort*)(ws + off);  off += (size_t)DD * KCAT * 2;          // 384 KB
  ushort* W2 = (ushort*)(ws + off);  off += (size_t)DD * KCAT * 2;          // 384 KB
  ushort* Abig1 = (ushort*)(ws + off); off += (size_t)M_TOT * KCAT * 2;     // 12 MB
  ushort* Abig2 = (ushort*)(ws + off); off += (size_t)M_TOT * KCAT * 2;     // 12 MB

  prep_kernel<<<dim3(512), 256, 0, stream>>>(x, w_rel1, w_root1, w_rel2,
                                             w_root2, aug, punct, bitsT, MT,
                                             xT, Abig1, W1, W2);
  // layer 1
  agg_gemm_kernel<<<dim3(4, 4, 32), 256, 0, stream>>>(bitsT, MT, xT, Abig1);
  main_gemm_kernel<0><<<dim3(4, 128), 256, 0, stream>>>(Abig1, W1, b1, Abig2,
                                                        hT, nullptr);
  // layer 2
  agg_gemm_kernel<<<dim3(4, 4, 32), 256, 0, stream>>>(bitsT, MT, hT, Abig2);
  main_gemm_kernel<1><<<dim3(4, 128), 256, 0, stream>>>(Abig2, W2, b2, nullptr,
                                                        nullptr, out);
}